// Round 7
// baseline (267.213 us; speedup 1.0000x reference)
//
#include <hip/hip_runtime.h>
#include <hip/hip_bf16.h>
#include <math.h>

// Fused GQA attention, MI355X/gfx950.
// B=2 S=2048 E=2048 H=16 G=4 D=128, causal, fp32 in/out, bf16 MFMA compute.
//
//   1. conv_x      : x fp32 -> bf16 [4096][2048]
//   2. transpose_w : Wq/Wk/Wv [nh][E][128] fp32 -> Wt [3072][2048] bf16 (B^T layout)
//   3. build_bias  : bq|bk|bv -> bc[3072] fp32
//   4. qkv_gemm    : bf16 MFMA GEMM (128^2 tile, BK=32, global_load_lds dbuf),
//                    flat grid 768 + XCD swizzle. Epilogue: +bias, Q pre-scaled,
//                    Q/K [bh][s][128], V transposed [bg][128][s] with k-index
//                    sigma-permutation (swap bits 2<->3 of s) so attention's PV
//                    B-fragments are lane-local with ZERO exchange.
//   5. attn (v4)   : flash attention on 32x32x16 MFMA. 256 blocks x 4 waves,
//                    wave owns 32 q rows (halves LDS bytes/FLOP vs 16x16).
//                    Pair-balanced {j,15-j} => uniform 34 KV-tiles/block.
//                    XCD owns one (b,g) => KV fits 4MB XCD L2. KVBLK=64,
//                    double-buffered global_load_lds staging. XOR bank swizzle:
//                    K tile (256B rows) 4-bit key (row&15)<<4 => 2-way (free);
//                    V tile (128B rows) 3-bit key (row&7)<<4 => 4-way.
//                    Swapped QK^T => softmax lane-local (32 vals + 1 shfl);
//                    sigma-permuted V makes P fragments register-direct.
//                    Defer-max (THR=8), setprio around MFMA clusters.

typedef __attribute__((ext_vector_type(8))) short bf16x8;
typedef __attribute__((ext_vector_type(4))) short s16x4;
typedef __attribute__((ext_vector_type(4))) float f32x4;
typedef __attribute__((ext_vector_type(16))) float f32x16;

#define LOG2E 1.4426950408889634f

__device__ __forceinline__ short f2bf(float f) {
  union { float f; unsigned u; } v; v.f = f;
  unsigned r = v.u + 0x7FFFu + ((v.u >> 16) & 1u);
  return (short)(r >> 16);
}

__device__ __forceinline__ short hwbf(float f) {
  __hip_bfloat16 h = __float2bfloat16(f);
  return *(short*)&h;
}

__device__ __forceinline__ unsigned pkbf(float a, float b) {
  return (unsigned)(unsigned short)hwbf(a) | ((unsigned)(unsigned short)hwbf(b) << 16);
}

__device__ __forceinline__ void async16(const void* g, void* l) {
  __builtin_amdgcn_global_load_lds(
      (const __attribute__((address_space(1))) void*)g,
      (__attribute__((address_space(3))) void*)l, 16, 0, 0);
}

__device__ __forceinline__ f32x4 mfma16(bf16x8 a, bf16x8 b, f32x4 c) {
  return __builtin_amdgcn_mfma_f32_16x16x32_bf16(a, b, c, 0, 0, 0);
}

__device__ __forceinline__ f32x16 mfma32(bf16x8 a, bf16x8 b, f32x16 c) {
  return __builtin_amdgcn_mfma_f32_32x32x16_bf16(a, b, c, 0, 0, 0);
}

// ---------------------------------------------------------------- prep kernels

__global__ void conv_x(const float4* __restrict__ x, s16x4* __restrict__ xb) {
  const int i = blockIdx.x * 256 + threadIdx.x;
  float4 v = x[i];
  s16x4 o;
  o[0] = f2bf(v.x); o[1] = f2bf(v.y); o[2] = f2bf(v.z); o[3] = f2bf(v.w);
  xb[i] = o;
}

__global__ void transpose_w(const float* __restrict__ src, short* __restrict__ wt, int c0) {
  __shared__ float t[32][33];
  const int hh = blockIdx.z;
  const int e0 = blockIdx.x * 32, d0 = blockIdx.y * 32;
  const int tx = threadIdx.x, ty = threadIdx.y;  // (32, 8)
  const float* s = src + (size_t)hh * 2048 * 128;
#pragma unroll
  for (int i = ty; i < 32; i += 8)
    t[i][tx] = s[(size_t)(e0 + i) * 128 + d0 + tx];
  __syncthreads();
#pragma unroll
  for (int i = ty; i < 32; i += 8)
    wt[(size_t)(c0 + hh * 128 + d0 + i) * 2048 + e0 + tx] = f2bf(t[tx][i]);
}

__global__ void build_bias(const float* __restrict__ bq, const float* __restrict__ bk,
                           const float* __restrict__ bv, float* __restrict__ bc) {
  const int c = blockIdx.x * 256 + threadIdx.x;
  float v;
  if (c < 2048)      v = bq[c];
  else if (c < 2560) v = bk[c - 2048];
  else               v = bv[c - 2560];
  bc[c] = v;
}

// ---------------------------------------------------------------- QKV GEMM

__global__ __launch_bounds__(256) void qkv_gemm(
    const short* __restrict__ xb, const short* __restrict__ wt,
    const float* __restrict__ bc,
    short* __restrict__ qb, short* __restrict__ kb, short* __restrict__ vt)
{
  constexpr int E = 2048, BK = 32;
  __shared__ short Al[2][128 * BK];
  __shared__ short Bl[2][128 * BK];
  const int tid = threadIdx.x;
  const int lane = tid & 63, wave = tid >> 6;
  const int wr = wave >> 1, wc = wave & 1;
  const int l16 = lane & 15, grp = lane >> 4;
  const int work = (blockIdx.x & 7) * 96 + (blockIdx.x >> 3);
  const int m0 = (work / 24) * 128, n0 = (work % 24) * 128;

  const int c1 = tid, c2 = tid + 256;
  const int r1 = c1 >> 2, s1 = c1 & 3, r2 = c2 >> 2, s2 = c2 & 3;

  f32x4 acc[4][4] = {};

  async16(xb + (size_t)(m0 + r1) * E + s1 * 8, (char*)Al[0] + c1 * 16);
  async16(xb + (size_t)(m0 + r2) * E + s2 * 8, (char*)Al[0] + c2 * 16);
  async16(wt + (size_t)(n0 + r1) * E + s1 * 8, (char*)Bl[0] + c1 * 16);
  async16(wt + (size_t)(n0 + r2) * E + s2 * 8, (char*)Bl[0] + c2 * 16);
  __syncthreads();

  const int nk = E / BK;  // 64
  for (int t = 0; t < nk; ++t) {
    const int cur = t & 1;
    if (t + 1 < nk) {
      const int k0 = (t + 1) * BK;
      async16(xb + (size_t)(m0 + r1) * E + k0 + s1 * 8, (char*)Al[cur ^ 1] + c1 * 16);
      async16(xb + (size_t)(m0 + r2) * E + k0 + s2 * 8, (char*)Al[cur ^ 1] + c2 * 16);
      async16(wt + (size_t)(n0 + r1) * E + k0 + s1 * 8, (char*)Bl[cur ^ 1] + c1 * 16);
      async16(wt + (size_t)(n0 + r2) * E + k0 + s2 * 8, (char*)Bl[cur ^ 1] + c2 * 16);
    }
    bf16x8 af[4], bfr[4];
#pragma unroll
    for (int mi = 0; mi < 4; ++mi)
      af[mi] = *(const bf16x8*)&Al[cur][(wr * 64 + mi * 16 + l16) * BK + grp * 8];
#pragma unroll
    for (int ni = 0; ni < 4; ++ni)
      bfr[ni] = *(const bf16x8*)&Bl[cur][(wc * 64 + ni * 16 + l16) * BK + grp * 8];
#pragma unroll
    for (int mi = 0; mi < 4; ++mi)
#pragma unroll
      for (int ni = 0; ni < 4; ++ni)
        acc[mi][ni] = mfma16(af[mi], bfr[ni], acc[mi][ni]);
    __syncthreads();
  }

  const float qscale = 0.08838834764831845f;  // 1/sqrt(128)
#pragma unroll
  for (int ni = 0; ni < 4; ++ni) {
    const int c = n0 + wc * 64 + ni * 16 + l16;
    const float bias = bc[c];
    const int d = c & 127;
#pragma unroll
    for (int mi = 0; mi < 4; ++mi) {
      const int rbase = m0 + wr * 64 + mi * 16 + grp * 4;
      const int b = rbase >> 11;
      const int s = rbase & 2047;
      f32x4 a = acc[mi][ni];
      if (c < 2048) {
        const int h = c >> 7;
        short* dst = qb + ((size_t)(b * 16 + h) * 2048 + s) * 128 + d;
#pragma unroll
        for (int r = 0; r < 4; ++r) dst[(size_t)r * 128] = f2bf((a[r] + bias) * qscale);
      } else if (c < 2560) {
        const int gi = (c >> 7) & 3;
        short* dst = kb + ((size_t)(b * 4 + gi) * 2048 + s) * 128 + d;
#pragma unroll
        for (int r = 0; r < 4; ++r) dst[(size_t)r * 128] = f2bf(a[r] + bias);
      } else {
        const int gi = (c >> 7) & 3;
        s16x4 pk;
#pragma unroll
        for (int r = 0; r < 4; ++r) pk[r] = f2bf(a[r] + bias);
        // sigma: swap bits 2<->3 of the s-column (s is 4-aligned here)
        const int vcol = (s & ~12) | ((s & 4) << 1) | ((s & 8) >> 1);
        *(s16x4*)&vt[((size_t)(b * 4 + gi) * 128 + d) * 2048 + vcol] = pk;
      }
    }
  }
}

// ---------------------------------------------------------------- attention v4

// Stage K tile [64][128]bf16 (256B rows, 4-bit XOR key) and V^T tile
// [128][64]bf16 (128B rows, 3-bit XOR key). 256 threads x 4 chunks of 16B per
// tile; swizzle applied via pre-swizzled GLOBAL source (LDS dest linear).
__device__ __forceinline__ void stageKV(char* kd, char* vd,
                                        const short* __restrict__ Kg,
                                        const short* __restrict__ Vg,
                                        int kv0, int tid) {
#pragma unroll
  for (int rd = 0; rd < 4; ++rd) {
    const int off = rd * 4096 + tid * 16;
    const int row = off >> 8, colb = off & 255;
    const int sc = colb ^ ((row & 15) << 4);
    async16(Kg + (size_t)(kv0 + row) * 128 + (sc >> 1), kd + off);
  }
#pragma unroll
  for (int rd = 0; rd < 4; ++rd) {
    const int off = rd * 4096 + tid * 16;
    const int row = off >> 7, colb = off & 127;
    const int sc = colb ^ ((row & 7) << 4);
    async16(Vg + (size_t)row * 2048 + kv0 + (sc >> 1), vd + off);
  }
}

__global__ __launch_bounds__(256) void attn(
    const short* __restrict__ qb, const short* __restrict__ kb,
    const short* __restrict__ vt, float* __restrict__ out)
{
  constexpr int S = 2048, D = 128;
  extern __shared__ char lds[];
  const int tid = threadIdx.x;
  const int lane = tid & 63, wave = tid >> 6;
  const int l32 = lane & 31;     // q column / LDS row index
  const int hhf = lane >> 5;     // half-group (k/D sub-slice)
  const int swzK = (l32 & 15) << 4;
  const int swzV = (l32 & 7) << 4;
  // XCD swizzle: 256 blocks; XCD c owns bg = c (KV 1MB fits 4MB XCD L2).
  const int work = (blockIdx.x & 7) * 32 + (blockIdx.x >> 3);
  const int bg = work >> 5;
  const int b = bg >> 2, g = bg & 3;
  const int h = g * 4 + ((work >> 3) & 3);
  const int x = work & 7;        // pair {x, 15-x}

  const short* Qg = qb + (size_t)(b * 16 + h) * S * D;
  const short* Kg = kb + (size_t)(b * 4 + g) * S * D;
  const short* Vg = vt + (size_t)(b * 4 + g) * (size_t)D * S;

#pragma unroll
  for (int p = 0; p < 2; ++p) {
    const int jj = p ? (15 - x) : x;
    const int q0 = jj * 128 + wave * 32;   // this wave's 32 q rows
    const int nt = 2 * (jj + 1);

    // Q fragments (B-operand of mfma(K,Q)): col q=l32, k-slice = c*16 + hhf*8
    bf16x8 qf[8];
#pragma unroll
    for (int c = 0; c < 8; ++c)
      qf[c] = *(const bf16x8*)&Qg[(size_t)(q0 + l32) * D + c * 16 + hhf * 8];

    f32x16 o[4] = {};              // O^T: d = db*32 + (r&3)+8*(r>>2)+4*hhf, q = l32
    float mrun = -INFINITY, lrun = 0.f;

    stageKV(lds, lds + 32768, Kg, Vg, 0, tid);
    __syncthreads();

    for (int t = 0; t < nt; ++t) {
      const int kv0 = t << 6;
      const int cur = t & 1;
      if (t + 1 < nt)
        stageKV(lds + (cur ^ 1) * 16384, lds + 32768 + (cur ^ 1) * 16384,
                Kg, Vg, kv0 + 64, tid);
      const char* Kb = lds + cur * 16384;
      const char* Vb = lds + 32768 + cur * 16384;

      if (kv0 <= q0 + 31) {   // wave-uniform guard: skip fully-masked tiles
        // ---- QK^T: ST[k][q]; A=K rows k, B=Q. k = kt*32 + (r&3)+8*(r>>2)+4*hhf
        f32x16 st[2] = {};
        __builtin_amdgcn_s_setprio(1);
#pragma unroll
        for (int c = 0; c < 8; ++c) {
          const int X = c * 32 + hhf * 16;
          bf16x8 k0 = *(const bf16x8*)(Kb + (size_t)l32 * 256 + (X ^ swzK));
          st[0] = mfma32(k0, qf[c], st[0]);
          bf16x8 k1 = *(const bf16x8*)(Kb + (size_t)(32 + l32) * 256 + (X ^ swzK));
          st[1] = mfma32(k1, qf[c], st[1]);
        }
        __builtin_amdgcn_s_setprio(0);

        if (kv0 + 63 > q0) {   // diagonal region: causal mask
          const int qa = q0 + l32;
#pragma unroll
          for (int r = 0; r < 16; ++r) {
            const int kl = (r & 3) + 8 * (r >> 2) + 4 * hhf;
            if (kv0 + kl > qa)      st[0][r] = -INFINITY;
            if (kv0 + 32 + kl > qa) st[1][r] = -INFINITY;
          }
        }

        // ---- online softmax: 32 vals lane-local, one shfl (lanes l, l+32 share q)
        float tmax = -INFINITY;
#pragma unroll
        for (int r = 0; r < 16; ++r) {
          tmax = fmaxf(tmax, st[0][r]);
          tmax = fmaxf(tmax, st[1][r]);
        }
        tmax = fmaxf(tmax, __shfl_xor(tmax, 32));
        float fac = 1.0f;
        if (!__all(tmax <= mrun + 8.0f)) {   // defer-max THR=8
          const float mn = fmaxf(mrun, tmax);
          fac = exp2f((mrun - mn) * LOG2E);
#pragma unroll
          for (int db = 0; db < 4; ++db) o[db] *= fac;
          mrun = mn;
        }
        float lsum = 0.f;
        float ps0[16], ps1[16];
#pragma unroll
        for (int r = 0; r < 16; ++r) {
          ps0[r] = exp2f((st[0][r] - mrun) * LOG2E); lsum += ps0[r];
          ps1[r] = exp2f((st[1][r] - mrun) * LOG2E); lsum += ps1[r];
        }
        lsum += __shfl_xor(lsum, 32);
        lrun = lrun * fac + lsum;

        // ---- P fragments: with sigma-permuted V, B-frag(kbi) is lane-local:
        //   frag j = ps_t[8*(kbi&1) + j], t = kbi>>1
        bf16x8 pf[4];
#pragma unroll
        for (int kbi = 0; kbi < 4; ++kbi) {
          union { unsigned u[4]; bf16x8 v; } tu;
          const int c0 = 8 * (kbi & 1);
          if (kbi < 2) {
            tu.u[0] = pkbf(ps0[c0 + 0], ps0[c0 + 1]);
            tu.u[1] = pkbf(ps0[c0 + 2], ps0[c0 + 3]);
            tu.u[2] = pkbf(ps0[c0 + 4], ps0[c0 + 5]);
            tu.u[3] = pkbf(ps0[c0 + 6], ps0[c0 + 7]);
          } else {
            tu.u[0] = pkbf(ps1[c0 + 0], ps1[c0 + 1]);
            tu.u[1] = pkbf(ps1[c0 + 2], ps1[c0 + 3]);
            tu.u[2] = pkbf(ps1[c0 + 4], ps1[c0 + 5]);
            tu.u[3] = pkbf(ps1[c0 + 6], ps1[c0 + 7]);
          }
          pf[kbi] = tu.v;
        }

        // ---- PV: O^T[d][q] += V^T * P  (A=V^T rows d, stored sigma-permuted)
        __builtin_amdgcn_s_setprio(1);
#pragma unroll
        for (int kbi = 0; kbi < 4; ++kbi) {
          const int X = kbi * 32 + hhf * 16;
#pragma unroll
          for (int db = 0; db < 4; ++db) {
            bf16x8 vf = *(const bf16x8*)(Vb + (size_t)(db * 32 + l32) * 128 + (X ^ swzV));
            o[db] = mfma32(vf, pf[kbi], o[db]);
          }
        }
        __builtin_amdgcn_s_setprio(0);
      }
      __syncthreads();  // stage(t+1) drained + all reads of cur done
    }

    const float inv = 1.f / lrun;
    float* orow = out + ((size_t)b * S + q0 + l32) * 2048 + h * D;
#pragma unroll
    for (int db = 0; db < 4; ++db)
#pragma unroll
      for (int rq = 0; rq < 4; ++rq) {
        f32x4 w;
        w[0] = o[db][4 * rq + 0] * inv;
        w[1] = o[db][4 * rq + 1] * inv;
        w[2] = o[db][4 * rq + 2] * inv;
        w[3] = o[db][4 * rq + 3] * inv;
        *(f32x4*)&orow[db * 32 + 8 * rq + 4 * hhf] = w;
      }
  }
}

// ---------------------------------------------------------------- launch

extern "C" void kernel_launch(void* const* d_in, const int* in_sizes, int n_in,
                              void* d_out, int out_size, void* d_ws, size_t ws_size,
                              hipStream_t stream) {
  const float* x  = (const float*)d_in[0];
  const float* Wq = (const float*)d_in[1];
  const float* bq = (const float*)d_in[2];
  const float* Wk = (const float*)d_in[3];
  const float* bk = (const float*)d_in[4];
  const float* Wv = (const float*)d_in[5];
  const float* bv = (const float*)d_in[6];
  float* out = (float*)d_out;

  char* ws = (char*)d_ws;
  short* xb = (short*)ws;                                         // 16 MB
  short* wt = (short*)(ws + (size_t)16 * 1024 * 1024);            // 12 MB
  float* bc = (float*)(ws + (size_t)28 * 1024 * 1024);            // 16 KB slot
  short* qb = (short*)(ws + (size_t)28 * 1024 * 1024 + 65536);    // 16 MB
  short* kb = (short*)((char*)qb + (size_t)16 * 1024 * 1024);     // 4 MB
  short* vt = (short*)((char*)kb + (size_t)4 * 1024 * 1024);      // 4 MB

  conv_x<<<8192, 256, 0, stream>>>((const float4*)x, (s16x4*)xb);
  dim3 tb(32, 8);
  transpose_w<<<dim3(64, 4, 16), tb, 0, stream>>>(Wq, wt, 0);
  transpose_w<<<dim3(64, 4, 4),  tb, 0, stream>>>(Wk, wt, 2048);
  transpose_w<<<dim3(64, 4, 4),  tb, 0, stream>>>(Wv, wt, 2560);
  build_bias<<<12, 256, 0, stream>>>(bq, bk, bv, bc);
  qkv_gemm<<<768, 256, 0, stream>>>(xb, wt, bc, qb, kb, vt);

  (void)hipFuncSetAttribute((const void*)attn, hipFuncAttributeMaxDynamicSharedMemorySize, 65536);
  attn<<<256, 256, 65536, stream>>>(qb, kb, vt, out);
}

// Round 8
// 267.208 us; speedup vs baseline: 1.0000x; 1.0000x over previous
//
#include <hip/hip_runtime.h>
#include <hip/hip_bf16.h>
#include <math.h>

// Fused GQA attention, MI355X/gfx950.
// B=2 S=2048 E=2048 H=16 G=4 D=128, causal, fp32 in/out, bf16 MFMA compute.
//
//   1. conv_x      : x fp32 -> bf16 [4096][2048]
//   2. transpose_w : Wq/Wk/Wv [nh][E][128] fp32 -> Wt [3072][2048] bf16 (B^T layout)
//   3. build_bias  : bq|bk|bv -> bc[3072] fp32
//   4. qkv_gemm    : bf16 MFMA GEMM (128^2 tile, BK=32, global_load_lds dbuf),
//                    flat grid 768 + XCD swizzle. Epilogue: +bias, Q pre-scaled,
//                    Q/K [bh][s][128], V transposed [bg][128][s] with k-index
//                    sigma-permutation (swap bits 2<->3 of s) so attention's PV
//                    B-fragments are lane-local with ZERO exchange.
//   5. attn (v5)   : v4 compute structure (32x32x16 MFMA, swapped QK^T,
//                    lane-local softmax, sigma-permuted V, XOR swizzles)
//                    with a T4 counted-vmcnt schedule: 3 LDS buffer sets
//                    (96KB), prefetch distance 2, two raw s_barriers/iter,
//                    s_waitcnt vmcnt(16/8/0) - never 0 in steady state.
//                    Stage loads stay in flight across barriers (m218/AITER
//                    pattern) instead of the __syncthreads vmcnt(0) drain
//                    that cost ~5K cycles/iteration in v4.

typedef __attribute__((ext_vector_type(8))) short bf16x8;
typedef __attribute__((ext_vector_type(4))) short s16x4;
typedef __attribute__((ext_vector_type(4))) float f32x4;
typedef __attribute__((ext_vector_type(16))) float f32x16;

#define LOG2E 1.4426950408889634f

__device__ __forceinline__ short f2bf(float f) {
  union { float f; unsigned u; } v; v.f = f;
  unsigned r = v.u + 0x7FFFu + ((v.u >> 16) & 1u);
  return (short)(r >> 16);
}

__device__ __forceinline__ short hwbf(float f) {
  __hip_bfloat16 h = __float2bfloat16(f);
  return *(short*)&h;
}

__device__ __forceinline__ unsigned pkbf(float a, float b) {
  return (unsigned)(unsigned short)hwbf(a) | ((unsigned)(unsigned short)hwbf(b) << 16);
}

__device__ __forceinline__ void async16(const void* g, void* l) {
  __builtin_amdgcn_global_load_lds(
      (const __attribute__((address_space(1))) void*)g,
      (__attribute__((address_space(3))) void*)l, 16, 0, 0);
}

__device__ __forceinline__ f32x4 mfma16(bf16x8 a, bf16x8 b, f32x4 c) {
  return __builtin_amdgcn_mfma_f32_16x16x32_bf16(a, b, c, 0, 0, 0);
}

__device__ __forceinline__ f32x16 mfma32(bf16x8 a, bf16x8 b, f32x16 c) {
  return __builtin_amdgcn_mfma_f32_32x32x16_bf16(a, b, c, 0, 0, 0);
}

// ---------------------------------------------------------------- prep kernels

__global__ void conv_x(const float4* __restrict__ x, s16x4* __restrict__ xb) {
  const int i = blockIdx.x * 256 + threadIdx.x;
  float4 v = x[i];
  s16x4 o;
  o[0] = f2bf(v.x); o[1] = f2bf(v.y); o[2] = f2bf(v.z); o[3] = f2bf(v.w);
  xb[i] = o;
}

__global__ void transpose_w(const float* __restrict__ src, short* __restrict__ wt, int c0) {
  __shared__ float t[32][33];
  const int hh = blockIdx.z;
  const int e0 = blockIdx.x * 32, d0 = blockIdx.y * 32;
  const int tx = threadIdx.x, ty = threadIdx.y;  // (32, 8)
  const float* s = src + (size_t)hh * 2048 * 128;
#pragma unroll
  for (int i = ty; i < 32; i += 8)
    t[i][tx] = s[(size_t)(e0 + i) * 128 + d0 + tx];
  __syncthreads();
#pragma unroll
  for (int i = ty; i < 32; i += 8)
    wt[(size_t)(c0 + hh * 128 + d0 + i) * 2048 + e0 + tx] = f2bf(t[tx][i]);
}

__global__ void build_bias(const float* __restrict__ bq, const float* __restrict__ bk,
                           const float* __restrict__ bv, float* __restrict__ bc) {
  const int c = blockIdx.x * 256 + threadIdx.x;
  float v;
  if (c < 2048)      v = bq[c];
  else if (c < 2560) v = bk[c - 2048];
  else               v = bv[c - 2560];
  bc[c] = v;
}

// ---------------------------------------------------------------- QKV GEMM

__global__ __launch_bounds__(256) void qkv_gemm(
    const short* __restrict__ xb, const short* __restrict__ wt,
    const float* __restrict__ bc,
    short* __restrict__ qb, short* __restrict__ kb, short* __restrict__ vt)
{
  constexpr int E = 2048, BK = 32;
  __shared__ short Al[2][128 * BK];
  __shared__ short Bl[2][128 * BK];
  const int tid = threadIdx.x;
  const int lane = tid & 63, wave = tid >> 6;
  const int wr = wave >> 1, wc = wave & 1;
  const int l16 = lane & 15, grp = lane >> 4;
  const int work = (blockIdx.x & 7) * 96 + (blockIdx.x >> 3);
  const int m0 = (work / 24) * 128, n0 = (work % 24) * 128;

  const int c1 = tid, c2 = tid + 256;
  const int r1 = c1 >> 2, s1 = c1 & 3, r2 = c2 >> 2, s2 = c2 & 3;

  f32x4 acc[4][4] = {};

  async16(xb + (size_t)(m0 + r1) * E + s1 * 8, (char*)Al[0] + c1 * 16);
  async16(xb + (size_t)(m0 + r2) * E + s2 * 8, (char*)Al[0] + c2 * 16);
  async16(wt + (size_t)(n0 + r1) * E + s1 * 8, (char*)Bl[0] + c1 * 16);
  async16(wt + (size_t)(n0 + r2) * E + s2 * 8, (char*)Bl[0] + c2 * 16);
  __syncthreads();

  const int nk = E / BK;  // 64
  for (int t = 0; t < nk; ++t) {
    const int cur = t & 1;
    if (t + 1 < nk) {
      const int k0 = (t + 1) * BK;
      async16(xb + (size_t)(m0 + r1) * E + k0 + s1 * 8, (char*)Al[cur ^ 1] + c1 * 16);
      async16(xb + (size_t)(m0 + r2) * E + k0 + s2 * 8, (char*)Al[cur ^ 1] + c2 * 16);
      async16(wt + (size_t)(n0 + r1) * E + k0 + s1 * 8, (char*)Bl[cur ^ 1] + c1 * 16);
      async16(wt + (size_t)(n0 + r2) * E + k0 + s2 * 8, (char*)Bl[cur ^ 1] + c2 * 16);
    }
    bf16x8 af[4], bfr[4];
#pragma unroll
    for (int mi = 0; mi < 4; ++mi)
      af[mi] = *(const bf16x8*)&Al[cur][(wr * 64 + mi * 16 + l16) * BK + grp * 8];
#pragma unroll
    for (int ni = 0; ni < 4; ++ni)
      bfr[ni] = *(const bf16x8*)&Bl[cur][(wc * 64 + ni * 16 + l16) * BK + grp * 8];
#pragma unroll
    for (int mi = 0; mi < 4; ++mi)
#pragma unroll
      for (int ni = 0; ni < 4; ++ni)
        acc[mi][ni] = mfma16(af[mi], bfr[ni], acc[mi][ni]);
    __syncthreads();
  }

  const float qscale = 0.08838834764831845f;  // 1/sqrt(128)
#pragma unroll
  for (int ni = 0; ni < 4; ++ni) {
    const int c = n0 + wc * 64 + ni * 16 + l16;
    const float bias = bc[c];
    const int d = c & 127;
#pragma unroll
    for (int mi = 0; mi < 4; ++mi) {
      const int rbase = m0 + wr * 64 + mi * 16 + grp * 4;
      const int b = rbase >> 11;
      const int s = rbase & 2047;
      f32x4 a = acc[mi][ni];
      if (c < 2048) {
        const int h = c >> 7;
        short* dst = qb + ((size_t)(b * 16 + h) * 2048 + s) * 128 + d;
#pragma unroll
        for (int r = 0; r < 4; ++r) dst[(size_t)r * 128] = f2bf((a[r] + bias) * qscale);
      } else if (c < 2560) {
        const int gi = (c >> 7) & 3;
        short* dst = kb + ((size_t)(b * 4 + gi) * 2048 + s) * 128 + d;
#pragma unroll
        for (int r = 0; r < 4; ++r) dst[(size_t)r * 128] = f2bf(a[r] + bias);
      } else {
        const int gi = (c >> 7) & 3;
        s16x4 pk;
#pragma unroll
        for (int r = 0; r < 4; ++r) pk[r] = f2bf(a[r] + bias);
        // sigma: swap bits 2<->3 of the s-column (s is 4-aligned here)
        const int vcol = (s & ~12) | ((s & 4) << 1) | ((s & 8) >> 1);
        *(s16x4*)&vt[((size_t)(b * 4 + gi) * 128 + d) * 2048 + vcol] = pk;
      }
    }
  }
}

// ---------------------------------------------------------------- attention v5

// Stage one KV tile set: K [64][128]bf16 (256B rows, 4-bit XOR key) and
// V^T [128][64]bf16 (128B rows, 3-bit XOR key) into one 32KB LDS set.
// Swizzle via pre-swizzled GLOBAL source (LDS dest linear).
__device__ __forceinline__ void stageKV(char* set,
                                        const short* __restrict__ Kg,
                                        const short* __restrict__ Vg,
                                        int kv0, int tid) {
#pragma unroll
  for (int rd = 0; rd < 4; ++rd) {
    const int off = rd * 4096 + tid * 16;
    const int row = off >> 8, colb = off & 255;
    const int sc = colb ^ ((row & 15) << 4);
    async16(Kg + (size_t)(kv0 + row) * 128 + (sc >> 1), set + off);
  }
#pragma unroll
  for (int rd = 0; rd < 4; ++rd) {
    const int off = rd * 4096 + tid * 16;
    const int row = off >> 7, colb = off & 127;
    const int sc = colb ^ ((row & 7) << 4);
    async16(Vg + (size_t)row * 2048 + kv0 + (sc >> 1), set + 16384 + off);
  }
}

__global__ __launch_bounds__(256) void attn(
    const short* __restrict__ qb, const short* __restrict__ kb,
    const short* __restrict__ vt, float* __restrict__ out)
{
  constexpr int S = 2048, D = 128;
  extern __shared__ char lds[];
  const int tid = threadIdx.x;
  const int lane = tid & 63, wave = tid >> 6;
  const int l32 = lane & 31;     // q column / LDS row index
  const int hhf = lane >> 5;     // half-group (k/D sub-slice)
  const int swzK = (l32 & 15) << 4;
  const int swzV = (l32 & 7) << 4;
  // XCD swizzle: 256 blocks; XCD c owns bg = c (KV 1MB fits 4MB XCD L2).
  const int work = (blockIdx.x & 7) * 32 + (blockIdx.x >> 3);
  const int bg = work >> 5;
  const int b = bg >> 2, g = bg & 3;
  const int h = g * 4 + ((work >> 3) & 3);
  const int x = work & 7;        // pair {x, 15-x}

  const short* Qg = qb + (size_t)(b * 16 + h) * S * D;
  const short* Kg = kb + (size_t)(b * 4 + g) * S * D;
  const short* Vg = vt + (size_t)(b * 4 + g) * (size_t)D * S;

#pragma unroll
  for (int p = 0; p < 2; ++p) {
    const int jj = p ? (15 - x) : x;
    const int q0 = jj * 128 + wave * 32;   // this wave's 32 q rows
    const int nt = 2 * (jj + 1);           // nt >= 2 always

    // Q fragments (B-operand of mfma(K,Q)): col q=l32, k-slice = c*16 + hhf*8
    bf16x8 qf[8];
#pragma unroll
    for (int c = 0; c < 8; ++c)
      qf[c] = *(const bf16x8*)&Qg[(size_t)(q0 + l32) * D + c * 16 + hhf * 8];

    f32x16 o[4] = {};              // O^T: d = db*32 + (r&3)+8*(r>>2)+4*hhf, q = l32
    float mrun = -INFINITY, lrun = 0.f;

    // phase entry: previous phase fully drained (vmcnt(0) on its last iter);
    // barrier so no wave still reads LDS before we restage.
    __builtin_amdgcn_s_barrier();
    stageKV(lds, Kg, Vg, 0, tid);
    stageKV(lds + 32768, Kg, Vg, 64, tid);

    int cb = 0;      // compute set for iter t  (t % 3)
    int sb = 2;      // stage set  = (t+2) % 3
    for (int t = 0; t < nt; ++t) {
      const int kv0 = t << 6;
      // B0: all waves finished compute(t-1) (reads of set (t-1)%3 == (t+2)%3)
      __builtin_amdgcn_s_barrier();
      if (t + 2 < nt) {
        stageKV(lds + sb * 32768, Kg, Vg, kv0 + 128, tid);
        asm volatile("s_waitcnt vmcnt(16)" ::: "memory");  // stage(t) done, 16 in flight
      } else if (t + 1 < nt) {
        asm volatile("s_waitcnt vmcnt(8)" ::: "memory");   // stage(t) done, 8 in flight
      } else {
        asm volatile("s_waitcnt vmcnt(0)" ::: "memory");   // last iter: full drain
      }
      // B1: set cb is resident for everyone
      __builtin_amdgcn_s_barrier();
      __builtin_amdgcn_sched_barrier(0);

      const char* Kb = lds + cb * 32768;
      const char* Vb = lds + cb * 32768 + 16384;

      if (kv0 <= q0 + 31) {   // wave-uniform guard: skip fully-masked tiles
        // ---- QK^T: ST[k][q]; A=K rows k, B=Q. k = kt*32 + (r&3)+8*(r>>2)+4*hhf
        f32x16 st[2] = {};
        __builtin_amdgcn_s_setprio(1);
#pragma unroll
        for (int c = 0; c < 8; ++c) {
          const int X = c * 32 + hhf * 16;
          bf16x8 k0 = *(const bf16x8*)(Kb + (size_t)l32 * 256 + (X ^ swzK));
          st[0] = mfma32(k0, qf[c], st[0]);
          bf16x8 k1 = *(const bf16x8*)(Kb + (size_t)(32 + l32) * 256 + (X ^ swzK));
          st[1] = mfma32(k1, qf[c], st[1]);
        }
        __builtin_amdgcn_s_setprio(0);

        if (kv0 + 63 > q0) {   // diagonal region: causal mask
          const int qa = q0 + l32;
#pragma unroll
          for (int r = 0; r < 16; ++r) {
            const int kl = (r & 3) + 8 * (r >> 2) + 4 * hhf;
            if (kv0 + kl > qa)      st[0][r] = -INFINITY;
            if (kv0 + 32 + kl > qa) st[1][r] = -INFINITY;
          }
        }

        // ---- online softmax: 32 vals lane-local, one shfl (lanes l, l+32 share q)
        float tmax = -INFINITY;
#pragma unroll
        for (int r = 0; r < 16; ++r) {
          tmax = fmaxf(tmax, st[0][r]);
          tmax = fmaxf(tmax, st[1][r]);
        }
        tmax = fmaxf(tmax, __shfl_xor(tmax, 32));
        float fac = 1.0f;
        if (!__all(tmax <= mrun + 8.0f)) {   // defer-max THR=8
          const float mn = fmaxf(mrun, tmax);
          fac = exp2f((mrun - mn) * LOG2E);
#pragma unroll
          for (int db = 0; db < 4; ++db) o[db] *= fac;
          mrun = mn;
        }
        float lsum = 0.f;
        float ps0[16], ps1[16];
#pragma unroll
        for (int r = 0; r < 16; ++r) {
          ps0[r] = exp2f((st[0][r] - mrun) * LOG2E); lsum += ps0[r];
          ps1[r] = exp2f((st[1][r] - mrun) * LOG2E); lsum += ps1[r];
        }
        lsum += __shfl_xor(lsum, 32);
        lrun = lrun * fac + lsum;

        // ---- P fragments: with sigma-permuted V, B-frag(kbi) is lane-local:
        //   frag j = ps_t[8*(kbi&1) + j], t = kbi>>1
        bf16x8 pf[4];
#pragma unroll
        for (int kbi = 0; kbi < 4; ++kbi) {
          union { unsigned u[4]; bf16x8 v; } tu;
          const int c0 = 8 * (kbi & 1);
          if (kbi < 2) {
            tu.u[0] = pkbf(ps0[c0 + 0], ps0[c0 + 1]);
            tu.u[1] = pkbf(ps0[c0 + 2], ps0[c0 + 3]);
            tu.u[2] = pkbf(ps0[c0 + 4], ps0[c0 + 5]);
            tu.u[3] = pkbf(ps0[c0 + 6], ps0[c0 + 7]);
          } else {
            tu.u[0] = pkbf(ps1[c0 + 0], ps1[c0 + 1]);
            tu.u[1] = pkbf(ps1[c0 + 2], ps1[c0 + 3]);
            tu.u[2] = pkbf(ps1[c0 + 4], ps1[c0 + 5]);
            tu.u[3] = pkbf(ps1[c0 + 6], ps1[c0 + 7]);
          }
          pf[kbi] = tu.v;
        }

        // ---- PV: O^T[d][q] += V^T * P  (A=V^T rows d, stored sigma-permuted)
        __builtin_amdgcn_s_setprio(1);
#pragma unroll
        for (int kbi = 0; kbi < 4; ++kbi) {
          const int X = kbi * 32 + hhf * 16;
#pragma unroll
          for (int db = 0; db < 4; ++db) {
            bf16x8 vf = *(const bf16x8*)(Vb + (size_t)(db * 32 + l32) * 128 + (X ^ swzV));
            o[db] = mfma32(vf, pf[kbi], o[db]);
          }
        }
        __builtin_amdgcn_s_setprio(0);
      }
      cb = (cb == 2) ? 0 : cb + 1;
      sb = (sb == 2) ? 0 : sb + 1;
    }

    const float inv = 1.f / lrun;
    float* orow = out + ((size_t)b * S + q0 + l32) * 2048 + h * D;
#pragma unroll
    for (int db = 0; db < 4; ++db)
#pragma unroll
      for (int rq = 0; rq < 4; ++rq) {
        f32x4 w;
        w[0] = o[db][4 * rq + 0] * inv;
        w[1] = o[db][4 * rq + 1] * inv;
        w[2] = o[db][4 * rq + 2] * inv;
        w[3] = o[db][4 * rq + 3] * inv;
        *(f32x4*)&orow[db * 32 + 8 * rq + 4 * hhf] = w;
      }
  }
}

// ---------------------------------------------------------------- launch

extern "C" void kernel_launch(void* const* d_in, const int* in_sizes, int n_in,
                              void* d_out, int out_size, void* d_ws, size_t ws_size,
                              hipStream_t stream) {
  const float* x  = (const float*)d_in[0];
  const float* Wq = (const float*)d_in[1];
  const float* bq = (const float*)d_in[2];
  const float* Wk = (const float*)d_in[3];
  const float* bk = (const float*)d_in[4];
  const float* Wv = (const float*)d_in[5];
  const float* bv = (const float*)d_in[6];
  float* out = (float*)d_out;

  char* ws = (char*)d_ws;
  short* xb = (short*)ws;                                         // 16 MB
  short* wt = (short*)(ws + (size_t)16 * 1024 * 1024);            // 12 MB
  float* bc = (float*)(ws + (size_t)28 * 1024 * 1024);            // 16 KB slot
  short* qb = (short*)(ws + (size_t)28 * 1024 * 1024 + 65536);    // 16 MB
  short* kb = (short*)((char*)qb + (size_t)16 * 1024 * 1024);     // 4 MB
  short* vt = (short*)((char*)kb + (size_t)4 * 1024 * 1024);      // 4 MB

  conv_x<<<8192, 256, 0, stream>>>((const float4*)x, (s16x4*)xb);
  dim3 tb(32, 8);
  transpose_w<<<dim3(64, 4, 16), tb, 0, stream>>>(Wq, wt, 0);
  transpose_w<<<dim3(64, 4, 4),  tb, 0, stream>>>(Wk, wt, 2048);
  transpose_w<<<dim3(64, 4, 4),  tb, 0, stream>>>(Wv, wt, 2560);
  build_bias<<<12, 256, 0, stream>>>(bq, bk, bv, bc);
  qkv_gemm<<<768, 256, 0, stream>>>(xb, wt, bc, qb, kb, vt);

  (void)hipFuncSetAttribute((const void*)attn, hipFuncAttributeMaxDynamicSharedMemorySize, 98304);
  attn<<<256, 256, 98304, stream>>>(qb, kb, vt, out);
}